// Round 9
// baseline (17072.479 us; speedup 1.0000x reference)
//
#include <hip/hip_runtime.h>
#include <math.h>

// Problem constants
#define BATCH 2
#define SEQ   2048
#define DM    768
#define NHD   12
#define NL    2
#define DFF   3072
#define DH    64
#define HW    256            // WIN // 2
#define MR    (BATCH*SEQ)    // 4096
#define EPSF  1e-5f

// R9: R5 baseline (relu + scale 0.125, both confirmed by orthogonality algebra
// R6-R8) with the b2 OFFSET BUG fixed: b2 is (L, D) so the layer offset is
// l*DM, not l*DFF. The old code read 1536 floats past b2 for layer 1 --
// deterministic garbage per-channel bias before the final LN = the constant
// sigma~0.19 "structural" diff seen in R1/R3/R5.
#define SCALE 0.125f

// ---------------------------------------------------------------------------
// Strip GEMM, all fp32:  C[m,n] = sum_k A[m,k]*W[n,k] + bias[n]  (opt ReLU)
// ---------------------------------------------------------------------------
#define GN 64
#define GM 16
__global__ __launch_bounds__(64) void g_mm(
    const float* __restrict__ A, const float* __restrict__ W,
    const float* __restrict__ bias, float* __restrict__ C,
    int M, int N, int K, int relu)
{
    __shared__ float Ws[GN][65];
    const int t  = threadIdx.x;
    const int n0 = blockIdx.x * GN;
    const int m0 = blockIdx.y * GM;

    float acc[GM];
#pragma unroll
    for (int mm = 0; mm < GM; ++mm) acc[mm] = 0.f;

    for (int k0 = 0; k0 < K; k0 += 64) {
        const float* wr = W + (size_t)(n0 + t) * K + k0;
#pragma unroll
        for (int c = 0; c < 64; ++c) Ws[t][c] = wr[c];
        __syncthreads();
        for (int kk = 0; kk < 64; ++kk) {
            const float wv = Ws[t][kk];
            const float* ac = A + (size_t)m0 * K + k0 + kk;
#pragma unroll
            for (int mm = 0; mm < GM; ++mm)
                acc[mm] = fmaf(ac[(size_t)mm * K], wv, acc[mm]);
        }
        __syncthreads();
    }

    const float bv = bias[n0 + t];
    for (int mm = 0; mm < GM; ++mm) {
        float v = acc[mm] + bv;
        if (relu) v = fmaxf(v, 0.f);
        C[(size_t)(m0 + mm) * N + n0 + t] = v;
    }
}

// ---------------------------------------------------------------------------
// Banded attention, one wave per (query i, head h, batch b). All fp32.
// ---------------------------------------------------------------------------
__global__ __launch_bounds__(64) void a_att(
    const float* __restrict__ q, const float* __restrict__ k,
    const float* __restrict__ v, float* __restrict__ o)
{
    const int i = blockIdx.x, h = blockIdx.y, b = blockIdx.z;
    const int t = threadIdx.x;
    __shared__ float p[2 * HW + 1];

    const size_t base = (size_t)b * SEQ * DM + (size_t)h * DH;
    const int jlo = (i - HW > 0) ? (i - HW) : 0;
    const int jhi = (i + HW < SEQ - 1) ? (i + HW) : (SEQ - 1);
    const int cnt = jhi - jlo + 1;

    const float qd = q[base + (size_t)i * DM + t] * SCALE;

    float mx = -3.0e38f;
    for (int jj = 0; jj < cnt; ++jj) {
        float s = qd * k[base + (size_t)(jlo + jj) * DM + t];
#pragma unroll
        for (int off = 32; off; off >>= 1) s += __shfl_xor(s, off);
        if (t == 0) p[jj] = s;
        mx = fmaxf(mx, s);
    }
    __syncthreads();

    float lsum = 0.f;
    for (int jj = t; jj < cnt; jj += 64) {
        float e = __expf(p[jj] - mx);
        p[jj] = e;
        lsum += e;
    }
#pragma unroll
    for (int off = 32; off; off >>= 1) lsum += __shfl_xor(lsum, off);
    const float inv = 1.f / lsum;
    __syncthreads();

    float acc = 0.f;
    for (int jj = 0; jj < cnt; ++jj)
        acc = fmaf(p[jj], v[base + (size_t)(jlo + jj) * DM + t], acc);

    o[base + (size_t)i * DM + t] = acc * inv;
}

// ---------------------------------------------------------------------------
// Residual + LayerNorm, one wave per row. All fp32.
// ---------------------------------------------------------------------------
__global__ __launch_bounds__(64) void a_ln(
    const float* __restrict__ xa, const float* __restrict__ yb,
    const float* __restrict__ g, const float* __restrict__ be,
    float* __restrict__ out)
{
    const int r = blockIdx.x, t = threadIdx.x;
    const size_t off = (size_t)r * DM;
    float sv[12];
    float s1 = 0.f, s2 = 0.f;
#pragma unroll
    for (int ii = 0; ii < 12; ++ii) {
        float vv = xa[off + t + 64 * ii] + yb[off + t + 64 * ii];
        sv[ii] = vv; s1 += vv; s2 += vv * vv;
    }
#pragma unroll
    for (int o2 = 32; o2; o2 >>= 1) {
        s1 += __shfl_xor(s1, o2);
        s2 += __shfl_xor(s2, o2);
    }
    const float mean = s1 * (1.f / 768.f);
    const float rstd = rsqrtf(s2 * (1.f / 768.f) - mean * mean + EPSF);
#pragma unroll
    for (int ii = 0; ii < 12; ++ii) {
        const int c = t + 64 * ii;
        out[off + c] = (sv[ii] - mean) * rstd * g[c] + be[c];
    }
}

// ---------------------------------------------------------------------------
// Host orchestration — R5 layout; ONLY change: b2 layer offset = l*DM (bD).
// ---------------------------------------------------------------------------
extern "C" void kernel_launch(void* const* d_in, const int* in_sizes, int n_in,
                              void* d_out, int out_size, void* d_ws, size_t ws_size,
                              hipStream_t stream) {
    (void)in_sizes; (void)n_in; (void)out_size; (void)ws_size;
    const float* src = (const float*)d_in[0];
    const float* qw  = (const float*)d_in[1];
    const float* qb  = (const float*)d_in[2];
    const float* kw  = (const float*)d_in[3];
    const float* kb  = (const float*)d_in[4];
    const float* vw  = (const float*)d_in[5];
    const float* vb  = (const float*)d_in[6];
    const float* ow  = (const float*)d_in[7];
    const float* ob  = (const float*)d_in[8];
    const float* w1  = (const float*)d_in[9];
    const float* b1  = (const float*)d_in[10];
    const float* w2  = (const float*)d_in[11];
    const float* b2  = (const float*)d_in[12];
    const float* g1  = (const float*)d_in[13];
    const float* be1 = (const float*)d_in[14];
    const float* g2  = (const float*)d_in[15];
    const float* be2 = (const float*)d_in[16];

    const size_t A = (size_t)MR * DM;
    float* S = (float*)d_ws;
    float* q_  = S + 0 * A;
    float* k_  = S + 1 * A;
    float* v_  = S + 2 * A;
    float* o_  = S + 3 * A;
    float* y_  = S + 4 * A;
    float* h1  = S + 5 * A;
    float* y2  = S + 6 * A;
    float* ffh = S + 7 * A;
    float* x1  = S + 8 * A;

    const dim3 gP(DM / GN, MR / GM);
    const dim3 gA(SEQ, NHD, BATCH);
    const dim3 gF1(DFF / GN, 1024 / GM);
    const dim3 gF2(DM / GN, 1024 / GM);

    const float* x = src;
    for (int l = 0; l < NL; ++l) {
        const size_t wD = (size_t)l * DM * DM;
        const size_t wF = (size_t)l * DFF * DM;
        const size_t bD = (size_t)l * DM;    // offsets for (L, DM) tensors
        const size_t bF = (size_t)l * DFF;   // offsets for (L, DFF) tensors

        g_mm<<<gP, 64, 0, stream>>>(x, qw + wD, qb + bD, q_, MR, DM, DM, 0);
        g_mm<<<gP, 64, 0, stream>>>(x, kw + wD, kb + bD, k_, MR, DM, DM, 0);
        g_mm<<<gP, 64, 0, stream>>>(x, vw + wD, vb + bD, v_, MR, DM, DM, 0);
        a_att<<<gA, 64, 0, stream>>>(q_, k_, v_, o_);
        g_mm<<<gP, 64, 0, stream>>>(o_, ow + wD, ob + bD, y_, MR, DM, DM, 0);
        a_ln<<<MR, 64, 0, stream>>>(x, y_, g1 + bD, be1 + bD, h1);
        for (int c = 0; c < 4; ++c) {
            const size_t rD = (size_t)c * 1024 * DM;
            g_mm<<<gF1, 64, 0, stream>>>(h1 + rD, w1 + wF, b1 + bF, ffh,
                                         1024, DFF, DM, 1);
            // b2 is (L, DM): offset bD — THE FIX (was bF = l*DFF, OOB for l=1)
            g_mm<<<gF2, 64, 0, stream>>>(ffh, w2 + wF, b2 + bD, y2 + rD,
                                         1024, DM, DFF, 0);
        }
        float* xo = (l == NL - 1) ? (float*)d_out : x1;
        a_ln<<<MR, 64, 0, stream>>>(h1, y2, g2 + bD, be2 + bD, xo);
        x = x1;
    }
}

// Round 10
// 1731.303 us; speedup vs baseline: 9.8611x; 9.8611x over previous
//
#include <hip/hip_runtime.h>
#include <math.h>

// Problem constants
#define BATCH 2
#define SEQ   2048
#define DM    768
#define NHD   12
#define NL    2
#define DFF   3072
#define DH    64
#define HW    256            // WIN // 2
#define MR    (BATCH*SEQ)    // 4096
#define EPSF  1e-5f
#define SCALE 0.125f         // DH^-0.5

typedef __attribute__((ext_vector_type(8))) __bf16 bf16x8;
typedef __attribute__((ext_vector_type(4))) float  f32x4;

__device__ __forceinline__ ushort f2bu(float f) {
    union { __bf16 h; ushort u; } c;
    c.h = (__bf16)f;
    return c.u;
}
__device__ __forceinline__ float bu2f(ushort u) {
    union { uint u; float f; } c;
    c.u = ((uint)u) << 16;
    return c.f;
}

// ---------------------------------------------------------------------------
// fp32 -> bf16 cast, 4 elems/thread (n divisible by 1024)
// ---------------------------------------------------------------------------
__global__ __launch_bounds__(256) void cvt(const float* __restrict__ in,
                                           ushort* __restrict__ out, int n)
{
    int i = (blockIdx.x * 256 + threadIdx.x) * 4;
    if (i >= n) return;
    float4 v = *(const float4*)(in + i);
    ushort4 o;
    o.x = f2bu(v.x); o.y = f2bu(v.y); o.z = f2bu(v.z); o.w = f2bu(v.w);
    *(ushort4*)(out + i) = o;
}

// ---------------------------------------------------------------------------
// MFMA GEMM: C[m,n] = A[m,:].W[n,:] + bias[n]  (opt ReLU), all operands bf16,
// bias fp32, C bf16. 256 thr = 4 waves; 64x64 tile; BK=32; wave = 32x32 via
// 2x2 mfma_f32_16x16x32_bf16.
// Fragment layouts (learn_hip m89/m91/m92, HW-verified):
//   A-frag: A[m = lane&15][k = (lane>>4)*8 + j]
//   B-frag: W[n = lane&15][k = (lane>>4)*8 + j]
//   C/D:    col(n) = lane&15, row(m) = (lane>>4)*4 + reg
// ---------------------------------------------------------------------------
#define BKP 40   // LDS pitch in bf16 (80 B rows: 16B-aligned, 2-way-max conflicts)

__global__ __launch_bounds__(256) void gemm_bf16(
    const ushort* __restrict__ A, const ushort* __restrict__ W,
    const float* __restrict__ bias, ushort* __restrict__ C,
    int M, int N, int K, int relu)
{
    __shared__ ushort As[64][BKP];
    __shared__ ushort Ws[64][BKP];

    const int t  = threadIdx.x;
    const int bm = blockIdx.y * 64;
    const int bn = blockIdx.x * 64;

    const int w    = t >> 6;
    const int wm   = (w >> 1) * 32;
    const int wn   = (w & 1) * 32;
    const int lane = t & 63;
    const int quad = lane >> 4;
    const int lrow = lane & 15;

    const int srow = t >> 2;           // 0..63
    const int skc  = (t & 3) * 8;      // 0,8,16,24

    const ushort* ap = A + (size_t)(bm + srow) * K + skc;
    const ushort* wp = W + (size_t)(bn + srow) * K + skc;

    f32x4 acc[2][2] = {};

    for (int k0 = 0; k0 < K; k0 += 32) {
        uint4 av = *(const uint4*)(ap + k0);
        uint4 wv = *(const uint4*)(wp + k0);
        *(uint4*)&As[srow][skc] = av;
        *(uint4*)&Ws[srow][skc] = wv;
        __syncthreads();

        bf16x8 af[2], bf[2];
#pragma unroll
        for (int i = 0; i < 2; ++i)
            af[i] = *(const bf16x8*)&As[wm + i * 16 + lrow][quad * 8];
#pragma unroll
        for (int j = 0; j < 2; ++j)
            bf[j] = *(const bf16x8*)&Ws[wn + j * 16 + lrow][quad * 8];

#pragma unroll
        for (int i = 0; i < 2; ++i)
#pragma unroll
            for (int j = 0; j < 2; ++j)
                acc[i][j] = __builtin_amdgcn_mfma_f32_16x16x32_bf16(
                    af[i], bf[j], acc[i][j], 0, 0, 0);
        __syncthreads();
    }

#pragma unroll
    for (int j = 0; j < 2; ++j) {
        const int col = bn + wn + j * 16 + lrow;
        const float bv = bias[col];
#pragma unroll
        for (int i = 0; i < 2; ++i) {
            const int rbase = bm + wm + i * 16 + quad * 4;
#pragma unroll
            for (int r = 0; r < 4; ++r) {
                float v = acc[i][j][r] + bv;
                if (relu) v = fmaxf(v, 0.f);
                C[(size_t)(rbase + r) * N + col] = f2bu(v);
            }
        }
    }
}

// ---------------------------------------------------------------------------
// Banded attention: block = (16 queries, head, batch), 256 thr. bf16 I/O,
// fp32 math. Scores LDS-resident over the 576-wide union window.
// ---------------------------------------------------------------------------
#define QT  16
#define NCH 9   // 9*64 = 576 >= 256+16+256

__global__ __launch_bounds__(256) void attn(
    const ushort* __restrict__ q, const ushort* __restrict__ k,
    const ushort* __restrict__ v, ushort* __restrict__ o)
{
    __shared__ float qs[QT][DH];
    __shared__ float kv[64][DH + 1];
    __shared__ float sc[QT][NCH * 64];
    __shared__ float rinv[QT];

    const int t  = threadIdx.x;
    const int i0 = blockIdx.x * QT;
    const int h  = blockIdx.y;
    const int b  = blockIdx.z;
    const size_t base = (size_t)b * SEQ * DM + (size_t)h * DH;

    if (t < 128) {
        int qi = t >> 3, d0 = (t & 7) * 8;
        uint4 raw = *(const uint4*)(q + base + (size_t)(i0 + qi) * DM + d0);
        const ushort* u = (const ushort*)&raw;
#pragma unroll
        for (int x = 0; x < 8; ++x) qs[qi][d0 + x] = bu2f(u[x]) * SCALE;
    }
    __syncthreads();

    const int jstart = i0 - HW;

    for (int c = 0; c < NCH; ++c) {
        const int j0 = jstart + c * 64;
#pragma unroll
        for (int e = 0; e < 2; ++e) {
            int idx = t + 256 * e;
            int jj = idx >> 3, d0 = (idx & 7) * 8;
            int j = j0 + jj;
            if (j >= 0 && j < SEQ) {
                uint4 raw = *(const uint4*)(k + base + (size_t)j * DM + d0);
                const ushort* u = (const ushort*)&raw;
#pragma unroll
                for (int x = 0; x < 8; ++x) kv[jj][d0 + x] = bu2f(u[x]);
            } else {
#pragma unroll
                for (int x = 0; x < 8; ++x) kv[jj][d0 + x] = 0.f;
            }
        }
        __syncthreads();
#pragma unroll
        for (int r = 0; r < 4; ++r) {
            int idx = t + 256 * r;
            int jj = idx & 63, qi = idx >> 6;
            float a = 0.f;
#pragma unroll
            for (int d = 0; d < DH; ++d) a = fmaf(qs[qi][d], kv[jj][d], a);
            int i = i0 + qi, j = j0 + jj;
            bool ok = (j >= 0) && (j < SEQ) && (j >= i - HW) && (j <= i + HW);
            sc[qi][c * 64 + jj] = ok ? a : -1e30f;
        }
        __syncthreads();
    }

    {
        const int r = t >> 4, l16 = t & 15;
        float mx = -1e30f;
        for (int cix = l16; cix < NCH * 64; cix += 16) mx = fmaxf(mx, sc[r][cix]);
#pragma unroll
        for (int off = 8; off; off >>= 1) mx = fmaxf(mx, __shfl_xor(mx, off));
        float sum = 0.f;
        for (int cix = l16; cix < NCH * 64; cix += 16) {
            float e = __expf(sc[r][cix] - mx);
            sc[r][cix] = e;
            sum += e;
        }
#pragma unroll
        for (int off = 8; off; off >>= 1) sum += __shfl_xor(sum, off);
        if (l16 == 0) rinv[r] = 1.f / sum;
    }
    __syncthreads();

    float oacc[4] = {0.f, 0.f, 0.f, 0.f};
    for (int c = 0; c < NCH; ++c) {
        const int j0 = jstart + c * 64;
#pragma unroll
        for (int e = 0; e < 2; ++e) {
            int idx = t + 256 * e;
            int jj = idx >> 3, d0 = (idx & 7) * 8;
            int j = j0 + jj;
            if (j >= 0 && j < SEQ) {
                uint4 raw = *(const uint4*)(v + base + (size_t)j * DM + d0);
                const ushort* u = (const ushort*)&raw;
#pragma unroll
                for (int x = 0; x < 8; ++x) kv[jj][d0 + x] = bu2f(u[x]);
            } else {
#pragma unroll
                for (int x = 0; x < 8; ++x) kv[jj][d0 + x] = 0.f;
            }
        }
        __syncthreads();
#pragma unroll
        for (int r = 0; r < 4; ++r) {
            int idx = t + 256 * r;
            int d = idx & 63, qi = idx >> 6;
            float a = oacc[r];
            const float* pr = &sc[qi][c * 64];
#pragma unroll
            for (int jj = 0; jj < 64; ++jj) a = fmaf(pr[jj], kv[jj][d], a);
            oacc[r] = a;
        }
        __syncthreads();
    }

#pragma unroll
    for (int r = 0; r < 4; ++r) {
        int idx = t + 256 * r;
        int d = idx & 63, qi = idx >> 6;
        o[base + (size_t)(i0 + qi) * DM + d] = f2bu(oacc[r] * rinv[qi]);
    }
}

// ---------------------------------------------------------------------------
// Residual + LayerNorm, one wave per row. bf16 in; bf16 out or fp32 (final).
// ---------------------------------------------------------------------------
__global__ __launch_bounds__(64) void add_ln(
    const ushort* __restrict__ xa, const ushort* __restrict__ yb,
    const float* __restrict__ g, const float* __restrict__ be,
    ushort* __restrict__ ob, float* __restrict__ of, int fin)
{
    const int r = blockIdx.x, t = threadIdx.x;
    const size_t off = (size_t)r * DM;
    float sv[12];
    float s1 = 0.f, s2 = 0.f;
#pragma unroll
    for (int ii = 0; ii < 12; ++ii) {
        float vv = bu2f(xa[off + t + 64 * ii]) + bu2f(yb[off + t + 64 * ii]);
        sv[ii] = vv; s1 += vv; s2 += vv * vv;
    }
#pragma unroll
    for (int o2 = 32; o2; o2 >>= 1) {
        s1 += __shfl_xor(s1, o2);
        s2 += __shfl_xor(s2, o2);
    }
    const float mean = s1 * (1.f / 768.f);
    const float rstd = rsqrtf(s2 * (1.f / 768.f) - mean * mean + EPSF);
#pragma unroll
    for (int ii = 0; ii < 12; ++ii) {
        const int c = t + 64 * ii;
        float v = (sv[ii] - mean) * rstd * g[c] + be[c];
        if (fin) of[off + c] = v;
        else     ob[off + c] = f2bu(v);
    }
}

// ---------------------------------------------------------------------------
// Host orchestration. ws (bf16 elems): weights 14.16M + activations 37.7M
// = 51.9M elems ~= 104 MB (R5 proved 113 MB works).
// ---------------------------------------------------------------------------
extern "C" void kernel_launch(void* const* d_in, const int* in_sizes, int n_in,
                              void* d_out, int out_size, void* d_ws, size_t ws_size,
                              hipStream_t stream) {
    (void)in_sizes; (void)n_in; (void)out_size; (void)ws_size;
    const float* src = (const float*)d_in[0];
    const float* qw  = (const float*)d_in[1];
    const float* qb  = (const float*)d_in[2];
    const float* kw  = (const float*)d_in[3];
    const float* kb  = (const float*)d_in[4];
    const float* vw  = (const float*)d_in[5];
    const float* vb  = (const float*)d_in[6];
    const float* ow  = (const float*)d_in[7];
    const float* ob  = (const float*)d_in[8];
    const float* w1  = (const float*)d_in[9];
    const float* b1  = (const float*)d_in[10];
    const float* w2  = (const float*)d_in[11];
    const float* b2  = (const float*)d_in[12];
    const float* g1  = (const float*)d_in[13];
    const float* be1 = (const float*)d_in[14];
    const float* g2  = (const float*)d_in[15];
    const float* be2 = (const float*)d_in[16];

    const size_t A   = (size_t)MR * DM;        // 3,145,728
    const size_t WD  = (size_t)NL * DM * DM;   // 1,179,648
    const size_t WF  = (size_t)NL * DFF * DM;  // 4,718,592

    ushort* p = (ushort*)d_ws;
    ushort* qwB = p; p += WD;
    ushort* kwB = p; p += WD;
    ushort* vwB = p; p += WD;
    ushort* owB = p; p += WD;
    ushort* w1B = p; p += WF;
    ushort* w2B = p; p += WF;
    ushort* xb  = p; p += A;
    ushort* qB  = p; p += A;
    ushort* kB  = p; p += A;
    ushort* vB  = p; p += A;
    ushort* oB  = p; p += A;
    ushort* yB  = p; p += A;
    ushort* h1  = p; p += A;
    ushort* y2  = p; p += A;
    ushort* ffh = p;                            // MR*DFF = 12.58M elems

    // weight + src conversion (all sizes divisible by 1024)
    cvt<<<(int)(WD / 1024), 256, 0, stream>>>(qw, qwB, (int)WD);
    cvt<<<(int)(WD / 1024), 256, 0, stream>>>(kw, kwB, (int)WD);
    cvt<<<(int)(WD / 1024), 256, 0, stream>>>(vw, vwB, (int)WD);
    cvt<<<(int)(WD / 1024), 256, 0, stream>>>(ow, owB, (int)WD);
    cvt<<<(int)(WF / 1024), 256, 0, stream>>>(w1, w1B, (int)WF);
    cvt<<<(int)(WF / 1024), 256, 0, stream>>>(w2, w2B, (int)WF);
    cvt<<<(int)(A  / 1024), 256, 0, stream>>>(src, xb, (int)A);

    const dim3 gP(DM / 64, MR / 64);    // (12, 64)
    const dim3 gF1(DFF / 64, MR / 64);  // (48, 64)
    const dim3 gA(SEQ / QT, NHD, BATCH);

    for (int l = 0; l < NL; ++l) {
        const size_t wD = (size_t)l * DM * DM;
        const size_t wF = (size_t)l * DFF * DM;
        const size_t bD = (size_t)l * DM;   // (L, DM) tensors — incl. b2!
        const size_t bF = (size_t)l * DFF;  // (L, DFF) tensors

        gemm_bf16<<<gP, 256, 0, stream>>>(xb, qwB + wD, qb + bD, qB,
                                          MR, DM, DM, 0);
        gemm_bf16<<<gP, 256, 0, stream>>>(xb, kwB + wD, kb + bD, kB,
                                          MR, DM, DM, 0);
        gemm_bf16<<<gP, 256, 0, stream>>>(xb, vwB + wD, vb + bD, vB,
                                          MR, DM, DM, 0);
        attn<<<gA, 256, 0, stream>>>(qB, kB, vB, oB);
        gemm_bf16<<<gP, 256, 0, stream>>>(oB, owB + wD, ob + bD, yB,
                                          MR, DM, DM, 0);
        add_ln<<<MR, 64, 0, stream>>>(xb, yB, g1 + bD, be1 + bD,
                                      h1, nullptr, 0);
        gemm_bf16<<<gF1, 256, 0, stream>>>(h1, w1B + wF, b1 + bF, ffh,
                                           MR, DFF, DM, 1);
        gemm_bf16<<<gP, 256, 0, stream>>>(ffh, w2B + wF, b2 + bD, xb,
                                          MR, DM, DFF, 0);
        if (l == NL - 1)
            add_ln<<<MR, 64, 0, stream>>>(h1, xb, g2 + bD, be2 + bD,
                                          nullptr, (float*)d_out, 1);
        else
            add_ln<<<MR, 64, 0, stream>>>(h1, xb, g2 + bD, be2 + bD,
                                          xb, nullptr, 0);
    }
}